// Round 3
// baseline (343.683 us; speedup 1.0000x reference)
//
#include <hip/hip_runtime.h>
#include <hip/hip_bf16.h>

#define NPIX 4096
#define CCH  256
#define HID  64
#define BAT  4
#define XSTR 264   // proj LDS row stride (elems)

using f32x4 = __attribute__((ext_vector_type(4))) float;
using s16x8 = __attribute__((ext_vector_type(8))) short;
using u16x4 = __attribute__((ext_vector_type(4))) unsigned short;

__device__ __forceinline__ unsigned short f2bf(float f) {
    __hip_bfloat16 h = __float2bfloat16(f);
    return __builtin_bit_cast(unsigned short, h);
}
__device__ __forceinline__ float bf2f(unsigned short u) {
    unsigned int v = ((unsigned int)u) << 16;
    return __builtin_bit_cast(float, v);
}
__device__ __forceinline__ s16x8 ldg_frag(const unsigned short* p) {
    uint4 v = *reinterpret_cast<const uint4*>(p);
    return __builtin_bit_cast(s16x8, v);
}
__device__ __forceinline__ s16x8 lds_frag(const unsigned short* p) {
    return *reinterpret_cast<const s16x8*>(p);
}
// order-preserving float<->uint encoding (unsigned compare == float compare)
__device__ __forceinline__ unsigned int encf(float f) {
    unsigned int u = __builtin_bit_cast(unsigned int, f);
    return (u & 0x80000000u) ? ~u : (u | 0x80000000u);
}
__device__ __forceinline__ float decf(unsigned int e) {
    unsigned int u = (e & 0x80000000u) ? (e ^ 0x80000000u) : ~e;
    return __builtin_bit_cast(float, u);
}
__device__ __forceinline__ float sel4(float a0, float a1, float a2, float a3, int q) {
    float x = (q & 1) ? a1 : a0;
    float y = (q & 1) ? a3 : a2;
    return (q & 2) ? y : x;
}

// ---------------------------------------------------------------------------
// W conversion: Wq(64x256), Wk(64x256), Wv(256x256) fp32 -> row-major
// [384][256] bf16 hi + lo. Rows 0-63 q, 64-127 k, 128-383 v.
// ---------------------------------------------------------------------------
__global__ __launch_bounds__(256, 1) void wcvt_kernel(
    const float* __restrict__ Wq, const float* __restrict__ Wk,
    const float* __restrict__ Wv,
    unsigned short* __restrict__ Wh, unsigned short* __restrict__ Wl)
{
    int idx = (blockIdx.x * 256 + threadIdx.x) * 4;
    int r = idx >> 8, c = idx & 255;
    const float* src = (r < 64)  ? (Wq + r * CCH + c)
                     : (r < 128) ? (Wk + (r - 64) * CCH + c)
                                 : (Wv + (r - 128) * CCH + c);
    float4 v4 = *reinterpret_cast<const float4*>(src);
    float vv[4] = {v4.x, v4.y, v4.z, v4.w};
    u16x4 hv, lv;
    #pragma unroll
    for (int j = 0; j < 4; ++j) {
        unsigned short hb = f2bf(vv[j]);
        hv[j] = hb;
        lv[j] = f2bf(vv[j] - bf2f(hb));
    }
    *reinterpret_cast<u16x4*>(Wh + idx) = hv;
    *reinterpret_cast<u16x4*>(Wl + idx) = lv;
}

// ---------------------------------------------------------------------------
// MFMA projection. Block = (s, b, 32-pixel tile). x^T hi/lo bf16 in LDS.
// Per wave: 6 single htiles; 16 W-frags live (64 VGPR); 3 independent
// accumulators break the dependent-MFMA chain.
// ---------------------------------------------------------------------------
__global__ __launch_bounds__(256, 2) void proj_kernel(
    const float* __restrict__ x1, const float* __restrict__ x2,
    const unsigned short* __restrict__ Wh, const unsigned short* __restrict__ Wl,
    const float* __restrict__ bq, const float* __restrict__ bk,
    const float* __restrict__ bv,
    unsigned short* __restrict__ Qh, unsigned short* __restrict__ Ql,
    unsigned short* __restrict__ Kh, unsigned short* __restrict__ Kl,
    unsigned short* __restrict__ Vt)
{
    __shared__ unsigned short xs_h[32][XSTR];
    __shared__ unsigned short xs_l[32][XSTR];

    const int Lb = blockIdx.x;
    const int sb = Lb & 7;              // XCD-locality swizzle
    const int tile = Lb >> 3;
    const int s = sb >> 2, b = sb & 3;
    const float* x = s ? x2 : x1;
    const int n0 = tile * 32;
    const int t = threadIdx.x;
    const int lane = t & 63;
    const int w = __builtin_amdgcn_readfirstlane(t >> 6);
    const int quad = lane >> 4, lq = lane & 15;

    // stage x^T hi/lo into LDS
    {
        const int n = t & 31;
        const int g = t >> 5;
        const float* xb = x + (size_t)(b * CCH) * NPIX + n0;
        #pragma unroll
        for (int i = 0; i < 8; ++i) {
            int c0 = g * 4 + i * 32;
            u16x4 hv, lv;
            #pragma unroll
            for (int j = 0; j < 4; ++j) {
                float v = xb[(size_t)(c0 + j) * NPIX + n];
                unsigned short hb = f2bf(v);
                hv[j] = hb;
                lv[j] = f2bf(v - bf2f(hb));
            }
            *reinterpret_cast<u16x4*>(&xs_h[n][c0]) = hv;
            *reinterpret_cast<u16x4*>(&xs_l[n][c0]) = lv;
        }
    }
    __syncthreads();

    const int sbN = (s * BAT + b) * NPIX;
    const int sbC = (s * BAT + b) * CCH;

    for (int hloop = 0; hloop < 6; ++hloop) {
        const int idx = w * 6 + hloop;                  // wave-uniform, 0..23
        const int kind = idx < 4 ? 0 : (idx < 8 ? 1 : 2);

        s16x8 wfh[8], wfl[8];
        const unsigned short* wph = Wh + (size_t)(idx * 16 + lq) * CCH + quad * 8;
        const unsigned short* wpl = Wl + (size_t)(idx * 16 + lq) * CCH + quad * 8;
        #pragma unroll
        for (int ks = 0; ks < 8; ++ks) {
            wfh[ks] = ldg_frag(wph + ks * 32);
            wfl[ks] = ldg_frag(wpl + ks * 32);
        }

        #pragma unroll
        for (int ntile = 0; ntile < 2; ++ntile) {
            f32x4 aA = (f32x4){0.f, 0.f, 0.f, 0.f};
            f32x4 aB = (f32x4){0.f, 0.f, 0.f, 0.f};
            f32x4 aC = (f32x4){0.f, 0.f, 0.f, 0.f};
            const unsigned short* xrh = &xs_h[ntile * 16 + lq][quad * 8];
            const unsigned short* xrl = &xs_l[ntile * 16 + lq][quad * 8];

            if (kind == 2) {
                #pragma unroll
                for (int ks = 0; ks < 8; ++ks) {
                    s16x8 xh = lds_frag(xrh + ks * 32);
                    s16x8 xl = lds_frag(xrl + ks * 32);
                    aA = __builtin_amdgcn_mfma_f32_16x16x32_bf16(wfh[ks], xh, aA, 0, 0, 0);
                    aB = __builtin_amdgcn_mfma_f32_16x16x32_bf16(wfl[ks], xh, aB, 0, 0, 0);
                    aC = __builtin_amdgcn_mfma_f32_16x16x32_bf16(wfh[ks], xl, aC, 0, 0, 0);
                }
                int cbase = (idx - 8) * 16 + quad * 4;
                int nn = n0 + ntile * 16 + lq;
                #pragma unroll
                for (int reg = 0; reg < 4; ++reg) {
                    int c = cbase + reg;
                    float v = aA[reg] + aB[reg] + aC[reg] + bv[c];
                    Vt[(size_t)(sbC + c) * NPIX + nn] = f2bf(v);
                }
            } else {
                #pragma unroll
                for (int ks = 0; ks < 8; ++ks) {
                    s16x8 xh = lds_frag(xrh + ks * 32);
                    s16x8 xl = lds_frag(xrl + ks * 32);
                    aA = __builtin_amdgcn_mfma_f32_16x16x32_bf16(xh, wfh[ks], aA, 0, 0, 0);
                    aB = __builtin_amdgcn_mfma_f32_16x16x32_bf16(xh, wfl[ks], aB, 0, 0, 0);
                    aC = __builtin_amdgcn_mfma_f32_16x16x32_bf16(xl, wfh[ks], aC, 0, 0, 0);
                }
                unsigned short* dh = (kind ? Kh : Qh);
                unsigned short* dl = (kind ? Kl : Ql);
                const float* bias = (kind ? bk : bq);
                int hl = (kind ? (idx - 4) : idx) * 16 + lq;
                float bb = bias[hl];
                #pragma unroll
                for (int reg = 0; reg < 4; ++reg) {
                    int nn = n0 + ntile * 16 + quad * 4 + reg;
                    float v = aA[reg] + aB[reg] + aC[reg] + bb;
                    unsigned short hb = f2bf(v);
                    dh[(size_t)(sbN + nn) * HID + hl] = hb;
                    dl[(size_t)(sbN + nn) * HID + hl] = f2bf(v - bf2f(hb));
                }
            }
        }
    }
}

// ---------------------------------------------------------------------------
// Flash cross-attention v3.
//   S^T = K Q^T (split-bf16), online softmax with:
//     - running column max in LDS via ONE gated ds_max_u32/wave (monotone,
//       order-preserving uint encoding; reads and atomics separated by the
//       two barriers so all waves see identical maxima each iter)
//     - per-wave partial L in registers, merged once at epilogue
//     - Oacc rescale skipped when no column max changed (ballot)
//   O^T = V^T P^T. Loop: phase2(i) | B2 | PV(i), S(i+1), phase1(i+1) | B1.
// ---------------------------------------------------------------------------
__global__ __launch_bounds__(256, 2) void attn_kernel(
    const float* __restrict__ x1, const float* __restrict__ x2,
    const unsigned short* __restrict__ Qh, const unsigned short* __restrict__ Ql,
    const unsigned short* __restrict__ Kh, const unsigned short* __restrict__ Kl,
    const unsigned short* __restrict__ Vt,
    const float* __restrict__ gamma,
    float* __restrict__ out)
{
    __shared__ unsigned short PT[64 * 72];   // P^T [n][m], +8 pad
    __shared__ unsigned int pmaxI[64];       // running column max (encoded)
    __shared__ float Lsh[4][64];             // per-wave L partials (epilogue)

    const int Lb = blockIdx.x;
    const int g = Lb & 7;
    const int ntile = Lb >> 3;
    const int d = g >> 2, b = g & 3;
    const int s = d, r = 1 - d;
    const int n0 = ntile * 64;

    const int t = threadIdx.x;
    const int lane = t & 63;
    const int w = __builtin_amdgcn_readfirstlane(t >> 6);
    const int quad = lane >> 4, lq = lane & 15;

    const unsigned short* Qhb = Qh + (size_t)(s * BAT + b) * NPIX * HID;
    const unsigned short* Qlb = Ql + (size_t)(s * BAT + b) * NPIX * HID;
    const unsigned short* Khb = Kh + (size_t)(r * BAT + b) * NPIX * HID;
    const unsigned short* Klb = Kl + (size_t)(r * BAT + b) * NPIX * HID;
    const unsigned short* Vb  = Vt + (size_t)(r * BAT + b) * CCH * NPIX;

    if (t < 64) pmaxI[t] = 0x007FFFFFu;      // enc(-inf)

    // Q fragments, persistent
    s16x8 qhf[4][2], qlf[4][2];
    #pragma unroll
    for (int nt = 0; nt < 4; ++nt)
        #pragma unroll
        for (int ks = 0; ks < 2; ++ks) {
            int off = (n0 + nt * 16 + lq) * HID + ks * 32 + quad * 8;
            qhf[nt][ks] = ldg_frag(Qhb + off);
            qlf[nt][ks] = ldg_frag(Qlb + off);
        }

    f32x4 Oacc[4][4];
    #pragma unroll
    for (int rt = 0; rt < 4; ++rt)
        #pragma unroll
        for (int ct = 0; ct < 4; ++ct)
            Oacc[rt][ct] = (f32x4){0.f, 0.f, 0.f, 0.f};

    float Mi[4], Li[4];
    #pragma unroll
    for (int nt = 0; nt < 4; ++nt) { Mi[nt] = -3.0e38f; Li[nt] = 0.f; }

    // K(0), V(0) fragments
    s16x8 khf[2], klf[2], vf[4][2];
    {
        int ko = (w * 16 + lq) * HID + quad * 8;
        khf[0] = ldg_frag(Khb + ko);      khf[1] = ldg_frag(Khb + ko + 32);
        klf[0] = ldg_frag(Klb + ko);      klf[1] = ldg_frag(Klb + ko + 32);
        #pragma unroll
        for (int rt = 0; rt < 4; ++rt)
            #pragma unroll
            for (int ks = 0; ks < 2; ++ks)
                vf[rt][ks] = ldg_frag(Vb + (size_t)(w * 64 + rt * 16 + lq) * NPIX
                                         + ks * 32 + quad * 8);
    }
    __syncthreads();   // pmaxI init visible

    f32x4 Sacc[4];

    // ---- S(0) ----
    #pragma unroll
    for (int nt = 0; nt < 4; ++nt) Sacc[nt] = (f32x4){0.f, 0.f, 0.f, 0.f};
    #pragma unroll
    for (int ks = 0; ks < 2; ++ks)
        #pragma unroll
        for (int nt = 0; nt < 4; ++nt) {
            Sacc[nt] = __builtin_amdgcn_mfma_f32_16x16x32_bf16(khf[ks], qhf[nt][ks], Sacc[nt], 0, 0, 0);
            Sacc[nt] = __builtin_amdgcn_mfma_f32_16x16x32_bf16(khf[ks], qlf[nt][ks], Sacc[nt], 0, 0, 0);
            Sacc[nt] = __builtin_amdgcn_mfma_f32_16x16x32_bf16(klf[ks], qhf[nt][ks], Sacc[nt], 0, 0, 0);
        }
    // prefetch K(1)
    {
        int ko = (64 + w * 16 + lq) * HID + quad * 8;
        khf[0] = ldg_frag(Khb + ko);  khf[1] = ldg_frag(Khb + ko + 32);
        klf[0] = ldg_frag(Klb + ko);  klf[1] = ldg_frag(Klb + ko + 32);
    }
    // ---- phase1(0) ----
    {
        float pm[4];
        #pragma unroll
        for (int nt = 0; nt < 4; ++nt) {
            float p = fmaxf(fmaxf(Sacc[nt][0], Sacc[nt][1]),
                            fmaxf(Sacc[nt][2], Sacc[nt][3]));
            p = fmaxf(p, __shfl_xor(p, 16));
            p = fmaxf(p, __shfl_xor(p, 32));
            pm[nt] = p;
        }
        atomicMax(&pmaxI[quad * 16 + lq], encf(sel4(pm[0], pm[1], pm[2], pm[3], quad)));
    }
    __syncthreads();   // B1

    for (int it = 0; it < 64; ++it) {
        // ---- phase2(it): softmax from Sacc, write PT, update Mi/Li/Oacc ----
        {
            float Mn[4];
            bool chg = false;
            #pragma unroll
            for (int nt = 0; nt < 4; ++nt) {
                float mv = decf(pmaxI[nt * 16 + lq]);
                Mn[nt] = fmaxf(Mi[nt], mv);
                chg = chg || (Mn[nt] > Mi[nt]);
            }
            if (__ballot(chg)) {
                float al[4];
                #pragma unroll
                for (int nt = 0; nt < 4; ++nt) {
                    al[nt] = __expf(Mi[nt] - Mn[nt]);
                    Li[nt] *= al[nt];
                }
                #pragma unroll
                for (int rt = 0; rt < 4; ++rt)
                    #pragma unroll
                    for (int ct = 0; ct < 4; ++ct)
                        Oacc[rt][ct] *= al[ct];
            }
            #pragma unroll
            for (int nt = 0; nt < 4; ++nt) {
                Mi[nt] = Mn[nt];
                float p0 = __expf(Sacc[nt][0] - Mn[nt]);
                float p1 = __expf(Sacc[nt][1] - Mn[nt]);
                float p2 = __expf(Sacc[nt][2] - Mn[nt]);
                float p3 = __expf(Sacc[nt][3] - Mn[nt]);
                float ps = (p0 + p1) + (p2 + p3);
                ps += __shfl_xor(ps, 16);
                ps += __shfl_xor(ps, 32);
                Li[nt] += ps;
                u16x4 pk;
                pk[0] = f2bf(p0); pk[1] = f2bf(p1); pk[2] = f2bf(p2); pk[3] = f2bf(p3);
                *reinterpret_cast<u16x4*>(&PT[(nt * 16 + lq) * 72 + w * 16 + quad * 4]) = pk;
            }
        }
        __syncthreads();   // B2: PT(it) visible; atomics done only after this

        // ---- PV(it) ----
        #pragma unroll
        for (int ks = 0; ks < 2; ++ks) {
            s16x8 pf[4];
            #pragma unroll
            for (int ct = 0; ct < 4; ++ct)
                pf[ct] = lds_frag(&PT[(ct * 16 + lq) * 72 + ks * 32 + quad * 8]);
            #pragma unroll
            for (int rt = 0; rt < 4; ++rt)
                #pragma unroll
                for (int ct = 0; ct < 4; ++ct)
                    Oacc[rt][ct] = __builtin_amdgcn_mfma_f32_16x16x32_bf16(
                        vf[rt][ks], pf[ct], Oacc[rt][ct], 0, 0, 0);
        }
        // prefetch V(it+1)
        const int itv = (it < 63) ? it + 1 : 63;
        #pragma unroll
        for (int rt = 0; rt < 4; ++rt)
            #pragma unroll
            for (int ks = 0; ks < 2; ++ks)
                vf[rt][ks] = ldg_frag(Vb + (size_t)(w * 64 + rt * 16 + lq) * NPIX
                                         + itv * 64 + ks * 32 + quad * 8);

        // ---- S(it+1) ----
        #pragma unroll
        for (int nt = 0; nt < 4; ++nt) Sacc[nt] = (f32x4){0.f, 0.f, 0.f, 0.f};
        #pragma unroll
        for (int ks = 0; ks < 2; ++ks)
            #pragma unroll
            for (int nt = 0; nt < 4; ++nt) {
                Sacc[nt] = __builtin_amdgcn_mfma_f32_16x16x32_bf16(khf[ks], qhf[nt][ks], Sacc[nt], 0, 0, 0);
                Sacc[nt] = __builtin_amdgcn_mfma_f32_16x16x32_bf16(khf[ks], qlf[nt][ks], Sacc[nt], 0, 0, 0);
                Sacc[nt] = __builtin_amdgcn_mfma_f32_16x16x32_bf16(klf[ks], qhf[nt][ks], Sacc[nt], 0, 0, 0);
            }
        // prefetch K(it+2)
        const int itk = (it < 62) ? it + 2 : 63;
        {
            int ko = (itk * 64 + w * 16 + lq) * HID + quad * 8;
            khf[0] = ldg_frag(Khb + ko);  khf[1] = ldg_frag(Khb + ko + 32);
            klf[0] = ldg_frag(Klb + ko);  klf[1] = ldg_frag(Klb + ko + 32);
        }
        // ---- phase1(it+1) ----
        {
            float pm[4];
            #pragma unroll
            for (int nt = 0; nt < 4; ++nt) {
                float p = fmaxf(fmaxf(Sacc[nt][0], Sacc[nt][1]),
                                fmaxf(Sacc[nt][2], Sacc[nt][3]));
                p = fmaxf(p, __shfl_xor(p, 16));
                p = fmaxf(p, __shfl_xor(p, 32));
                pm[nt] = p;
            }
            atomicMax(&pmaxI[quad * 16 + lq], encf(sel4(pm[0], pm[1], pm[2], pm[3], quad)));
        }
        __syncthreads();   // B1
    }

    // ---- epilogue: merge per-wave L, then out = xq + gamma * O^T / L ----
    Lsh[w][quad * 16 + lq] = sel4(Li[0], Li[1], Li[2], Li[3], quad);
    __syncthreads();

    float inv[4];
    #pragma unroll
    for (int nt = 0; nt < 4; ++nt) {
        int i = nt * 16 + lq;
        float Lt = (Lsh[0][i] + Lsh[1][i]) + (Lsh[2][i] + Lsh[3][i]);
        inv[nt] = 1.0f / Lt;
    }

    const float* xq = d ? x2 : x1;
    const float gm = gamma[0];

    #pragma unroll
    for (int rt = 0; rt < 4; ++rt)
        #pragma unroll
        for (int ct = 0; ct < 4; ++ct)
            #pragma unroll
            for (int rg = 0; rg < 4; ++rg) {
                int c = w * 64 + rt * 16 + quad * 4 + rg;
                int nn = n0 + ct * 16 + lq;
                size_t src = (size_t)(b * CCH + c) * NPIX + nn;
                size_t dst = (size_t)((d * BAT + b) * CCH + c) * NPIX + nn;
                out[dst] = xq[src] + gm * Oacc[rt][ct][rg] * inv[ct];
            }
}

// ---------------------------------------------------------------------------
extern "C" void kernel_launch(void* const* d_in, const int* in_sizes, int n_in,
                              void* d_out, int out_size, void* d_ws, size_t ws_size,
                              hipStream_t stream) {
    (void)in_sizes; (void)n_in; (void)out_size; (void)ws_size;
    const float* x1 = (const float*)d_in[0];
    const float* x2 = (const float*)d_in[1];
    const float* Wq = (const float*)d_in[2];
    const float* bq = (const float*)d_in[3];
    const float* Wk = (const float*)d_in[4];
    const float* bk = (const float*)d_in[5];
    const float* Wv = (const float*)d_in[6];
    const float* bv = (const float*)d_in[7];
    const float* gm = (const float*)d_in[8];
    float* out = (float*)d_out;

    unsigned short* ws = (unsigned short*)d_ws;
    const size_t QKELEM = (size_t)2 * BAT * NPIX * HID;   // 2,097,152
    unsigned short* Qh = ws;
    unsigned short* Ql = Qh + QKELEM;
    unsigned short* Kh = Ql + QKELEM;
    unsigned short* Kl = Kh + QKELEM;
    unsigned short* Vt = Kl + QKELEM;                     // 8,388,608 elems
    unsigned short* Whc = Vt + (size_t)2 * BAT * CCH * NPIX;
    unsigned short* Wlc = Whc + 384 * CCH;

    wcvt_kernel<<<dim3(96), dim3(256), 0, stream>>>(Wq, Wk, Wv, Whc, Wlc);
    proj_kernel<<<dim3(1024), dim3(256), 0, stream>>>(
        x1, x2, Whc, Wlc, bq, bk, bv, Qh, Ql, Kh, Kl, Vt);
    attn_kernel<<<dim3(512), dim3(256), 0, stream>>>(
        x1, x2, Qh, Ql, Kh, Kl, Vt, gm, out);
}